// Round 1
// baseline (142.806 us; speedup 1.0000x reference)
//
#include <hip/hip_runtime.h>

#define NNODES 16384
#define NEDGES 524288
#define DDIM   128

// workspace layout (bytes)
#define OFF_DEG     0u         // int[16384]
#define OFF_ROWPTR  65536u     // int[16385]
#define OFF_FLAG    131328u    // int[1]  (1 => edges are int32, 0 => int64)
#define OFF_CURSOR  131584u    // int[16384]
#define OFF_COL     197120u    // int[524288]
#define ZERO_BYTES  197120u    // zero deg/rowptr/flag/cursor each launch

// Detect edge-index element width from data: if stored as int64, every odd
// int32 word is a high word == 0 (indices in [0,16384)). If int32, odd words
// are real indices, essentially never all zero over 1024 samples.
__global__ __launch_bounds__(256) void detect_k(const int* __restrict__ ei, int* __restrict__ flag) {
  int i = blockIdx.x * 256 + threadIdx.x;  // 0..1023
  if (ei[2 * i + 1] != 0) atomicOr(flag, 1);
}

__global__ __launch_bounds__(256) void count_k(const int* __restrict__ ei, const int* __restrict__ flag,
                                               int* __restrict__ deg) {
  int i = blockIdx.x * 256 + threadIdx.x;
  if (i < NEDGES) {
    int is32 = *flag;
    int d = is32 ? ei[NEDGES + i] : ei[2 * (NEDGES + i)];
    atomicAdd(&deg[d], 1);
  }
}

__global__ __launch_bounds__(1024) void scan_k(const int* __restrict__ deg, int* __restrict__ rowptr) {
  __shared__ int s[1024];
  int t = threadIdx.x;
  int base = t * 16;
  int v[16];
  int sum = 0;
#pragma unroll
  for (int j = 0; j < 16; ++j) { v[j] = deg[base + j]; sum += v[j]; }
  s[t] = sum;
  __syncthreads();
  for (int off = 1; off < 1024; off <<= 1) {
    int add = (t >= off) ? s[t - off] : 0;
    __syncthreads();
    s[t] += add;
    __syncthreads();
  }
  int run = (t == 0) ? 0 : s[t - 1];
#pragma unroll
  for (int j = 0; j < 16; ++j) { rowptr[base + j] = run; run += v[j]; }
  if (t == 1023) rowptr[NNODES] = run;
}

__global__ __launch_bounds__(256) void fill_k(const int* __restrict__ ei, const int* __restrict__ flag,
                                              const int* __restrict__ rowptr, int* __restrict__ cursor,
                                              int* __restrict__ col) {
  int i = blockIdx.x * 256 + threadIdx.x;
  if (i < NEDGES) {
    int is32 = *flag;
    int s = is32 ? ei[i] : ei[2 * i];
    int d = is32 ? ei[NEDGES + i] : ei[2 * (NEDGES + i)];
    int slot = rowptr[d] + atomicAdd(&cursor[d], 1);
    col[slot] = s;
  }
}

#define CAP 512  // max in-degree; Binomial(524288, 1/16384) ~ mean 32, P(>100) ~ 0
__global__ __launch_bounds__(128) void gather_k(const int* __restrict__ rowptr, const int* __restrict__ col,
                                                const float* __restrict__ x, float* __restrict__ agg) {
  int row = blockIdx.x;
  int t = threadIdx.x;  // 128 = one feature dim each
  int beg = rowptr[row];
  int k = rowptr[row + 1] - beg;
  if (k > CAP) k = CAP;
  __shared__ int s_col[CAP];
  __shared__ float s_kf[CAP];
  __shared__ int s_uniq;
  if (t == 0) s_uniq = 0;
  for (int j = t; j < k; j += 128) s_col[j] = col[beg + j];
  __syncthreads();
  int lu = 0;
  for (int j = t; j < k; j += 128) {
    int c = s_col[j];
    bool kp = true;
    for (int j2 = 0; j2 < j; ++j2)
      if (s_col[j2] == c) { kp = false; break; }
    s_kf[j] = kp ? 1.0f : 0.0f;
    lu += kp ? 1 : 0;
  }
  if (lu) atomicAdd(&s_uniq, lu);
  __syncthreads();
  int u = s_uniq;
  float dinv = 1.0f / (float)(u > 0 ? u : 1);
  float acc = 0.0f;
#pragma unroll 4
  for (int j = 0; j < k; ++j)
    acc += s_kf[j] * x[(size_t)s_col[j] * DDIM + t];
  agg[(size_t)row * DDIM + t] = acc * dinv;
}

// out = agg @ W^T + x @ B^T.  agg aliases out (each block reads only the rows
// it later writes; all reads complete before writes via barrier ordering).
__global__ __launch_bounds__(256) void gemm_k(const float* agg,
                                              const float* __restrict__ x,
                                              const float* __restrict__ W,
                                              const float* __restrict__ Bm,
                                              float* out) {
  __shared__ float sA[64][65];
  __shared__ float sB[128][65];
  int t = threadIdx.x;
  int tr = t >> 4;  // 0..15 -> 4 rows each
  int tc = t & 15;  // 0..15 -> 8 cols each (stride 16)
  int row0 = blockIdx.x * 64;
  float acc[4][8];
#pragma unroll
  for (int i = 0; i < 4; ++i)
#pragma unroll
    for (int j = 0; j < 8; ++j) acc[i][j] = 0.0f;

  for (int phase = 0; phase < 2; ++phase) {
    const float* A = phase ? x : agg;
    const float* Bmat = phase ? Bm : W;
    for (int kk = 0; kk < 128; kk += 64) {
      __syncthreads();
#pragma unroll
      for (int u = 0; u < 4; ++u) {
        int f = t + u * 256;          // 0..1023: 64 rows x 16 float4
        int r = f >> 4, kq = f & 15;
        float4 v = *reinterpret_cast<const float4*>(&A[(size_t)(row0 + r) * 128 + kk + kq * 4]);
        sA[r][kq * 4 + 0] = v.x; sA[r][kq * 4 + 1] = v.y;
        sA[r][kq * 4 + 2] = v.z; sA[r][kq * 4 + 3] = v.w;
      }
#pragma unroll
      for (int u = 0; u < 8; ++u) {
        int f = t + u * 256;          // 0..2047: 128 rows x 16 float4
        int r = f >> 4, kq = f & 15;
        float4 v = *reinterpret_cast<const float4*>(&Bmat[(size_t)r * 128 + kk + kq * 4]);
        sB[r][kq * 4 + 0] = v.x; sB[r][kq * 4 + 1] = v.y;
        sB[r][kq * 4 + 2] = v.z; sB[r][kq * 4 + 3] = v.w;
      }
      __syncthreads();
#pragma unroll 4
      for (int k = 0; k < 64; ++k) {
        float a[4], b[8];
#pragma unroll
        for (int i = 0; i < 4; ++i) a[i] = sA[tr * 4 + i][k];
#pragma unroll
        for (int j = 0; j < 8; ++j) b[j] = sB[tc + j * 16][k];
#pragma unroll
        for (int i = 0; i < 4; ++i)
#pragma unroll
          for (int j = 0; j < 8; ++j) acc[i][j] += a[i] * b[j];
      }
    }
  }
  __syncthreads();
#pragma unroll
  for (int i = 0; i < 4; ++i) {
    int r = row0 + tr * 4 + i;
#pragma unroll
    for (int j = 0; j < 8; ++j)
      out[(size_t)r * 128 + tc + j * 16] = acc[i][j];
  }
}

extern "C" void kernel_launch(void* const* d_in, const int* in_sizes, int n_in,
                              void* d_out, int out_size, void* d_ws, size_t ws_size,
                              hipStream_t stream) {
  const float* x = (const float*)d_in[0];
  const int* ei = (const int*)d_in[1];
  const float* W = (const float*)d_in[2];
  const float* Bm = (const float*)d_in[3];
  float* out = (float*)d_out;
  char* ws = (char*)d_ws;
  int* deg = (int*)(ws + OFF_DEG);
  int* rowptr = (int*)(ws + OFF_ROWPTR);
  int* flag = (int*)(ws + OFF_FLAG);
  int* cursor = (int*)(ws + OFF_CURSOR);
  int* col = (int*)(ws + OFF_COL);

  hipMemsetAsync(d_ws, 0, ZERO_BYTES, stream);
  detect_k<<<4, 256, 0, stream>>>(ei, flag);
  count_k<<<NEDGES / 256, 256, 0, stream>>>(ei, flag, deg);
  scan_k<<<1, 1024, 0, stream>>>(deg, rowptr);
  fill_k<<<NEDGES / 256, 256, 0, stream>>>(ei, flag, rowptr, cursor, col);
  gather_k<<<NNODES, 128, 0, stream>>>(rowptr, col, x, out);   // agg -> d_out
  gemm_k<<<NNODES / 64, 256, 0, stream>>>(out, x, W, Bm, out);
}

// Round 2
// 123.683 us; speedup vs baseline: 1.1546x; 1.1546x over previous
//
#include <hip/hip_runtime.h>

#define NNODES 16384
#define NEDGES 524288
#define DDIM   128

// workspace layout (bytes)
#define OFF_DEG     0u         // int[16384]
#define OFF_ROWPTR  65536u     // int[16385]
#define OFF_FLAG    131328u    // int[1]  (1 => edges are int32, 0 => int64)
#define OFF_CURSOR  131584u    // int[16384]
#define OFF_COL     197120u    // int[524288]
#define ZERO_BYTES  197120u

__global__ __launch_bounds__(256) void detect_k(const int* __restrict__ ei, int* __restrict__ flag) {
  int i = blockIdx.x * 256 + threadIdx.x;  // 0..1023
  if (ei[2 * i + 1] != 0) atomicOr(flag, 1);
}

__global__ __launch_bounds__(256) void count_k(const int* __restrict__ ei, const int* __restrict__ flag,
                                               int* __restrict__ deg) {
  int i = blockIdx.x * 256 + threadIdx.x;
  if (i < NEDGES) {
    int is32 = *flag;
    int d = is32 ? ei[NEDGES + i] : ei[2 * (NEDGES + i)];
    atomicAdd(&deg[d], 1);
  }
}

__global__ __launch_bounds__(1024) void scan_k(const int* __restrict__ deg, int* __restrict__ rowptr) {
  __shared__ int s[1024];
  int t = threadIdx.x;
  int base = t * 16;
  int v[16];
  int sum = 0;
#pragma unroll
  for (int j = 0; j < 16; ++j) { v[j] = deg[base + j]; sum += v[j]; }
  s[t] = sum;
  __syncthreads();
  for (int off = 1; off < 1024; off <<= 1) {
    int add = (t >= off) ? s[t - off] : 0;
    __syncthreads();
    s[t] += add;
    __syncthreads();
  }
  int run = (t == 0) ? 0 : s[t - 1];
#pragma unroll
  for (int j = 0; j < 16; ++j) { rowptr[base + j] = run; run += v[j]; }
  if (t == 1023) rowptr[NNODES] = run;
}

__global__ __launch_bounds__(256) void fill_k(const int* __restrict__ ei, const int* __restrict__ flag,
                                              const int* __restrict__ rowptr, int* __restrict__ cursor,
                                              int* __restrict__ col) {
  int i = blockIdx.x * 256 + threadIdx.x;
  if (i < NEDGES) {
    int is32 = *flag;
    int s = is32 ? ei[i] : ei[2 * i];
    int d = is32 ? ei[NEDGES + i] : ei[2 * (NEDGES + i)];
    int slot = rowptr[d] + atomicAdd(&cursor[d], 1);
    col[slot] = s;
  }
}

// mean in-degree 32 (Binomial(524288,1/16384)); max over 16384 rows ~60.
// CAP=128 is ~17 sigma beyond the mean: overflow prob ~1e-32.
#define CAP 128
#define RPB 8
// One row per 32-lane half-wave: all LDS traffic is intra-wave -> no barriers.
__global__ __launch_bounds__(256) void gather_k(const int* __restrict__ rowptr, const int* __restrict__ col,
                                                const float* __restrict__ x, float* __restrict__ agg) {
  __shared__ int   s_col[RPB][CAP];
  __shared__ float s_kf[RPB][CAP];
  int t = threadIdx.x;
  int lane = t & 31;   // float4 feature chunk
  int r = t >> 5;      // local row
  int row = blockIdx.x * RPB + r;
  int beg = rowptr[row];
  int k = rowptr[row + 1] - beg;
  if (k > CAP) k = CAP;

  for (int j = lane; j < k; j += 32) s_col[r][j] = col[beg + j];

  int lu = 0;
  for (int j = lane; j < k; j += 32) {
    int c = s_col[r][j];
    bool kp = true;
    for (int j2 = 0; j2 < j; ++j2)
      if (s_col[r][j2] == c) { kp = false; break; }
    s_kf[r][j] = kp ? 1.0f : 0.0f;
    lu += kp ? 1 : 0;
  }
#pragma unroll
  for (int off = 16; off; off >>= 1) lu += __shfl_xor(lu, off);
  float dinv = 1.0f / (float)(lu > 0 ? lu : 1);

  float4 acc0 = {0.f, 0.f, 0.f, 0.f}, acc1 = {0.f, 0.f, 0.f, 0.f};
  const float* xb = x + (size_t)lane * 4;
  int j = 0;
#pragma unroll 2
  for (; j + 2 <= k; j += 2) {
    int c0 = s_col[r][j], c1 = s_col[r][j + 1];
    float f0 = s_kf[r][j], f1 = s_kf[r][j + 1];
    float4 v0 = *reinterpret_cast<const float4*>(xb + (size_t)c0 * DDIM);
    float4 v1 = *reinterpret_cast<const float4*>(xb + (size_t)c1 * DDIM);
    acc0.x += f0 * v0.x; acc0.y += f0 * v0.y; acc0.z += f0 * v0.z; acc0.w += f0 * v0.w;
    acc1.x += f1 * v1.x; acc1.y += f1 * v1.y; acc1.z += f1 * v1.z; acc1.w += f1 * v1.w;
  }
  if (j < k) {
    int c0 = s_col[r][j];
    float f0 = s_kf[r][j];
    float4 v0 = *reinterpret_cast<const float4*>(xb + (size_t)c0 * DDIM);
    acc0.x += f0 * v0.x; acc0.y += f0 * v0.y; acc0.z += f0 * v0.z; acc0.w += f0 * v0.w;
  }
  float4 res;
  res.x = (acc0.x + acc1.x) * dinv;
  res.y = (acc0.y + acc1.y) * dinv;
  res.z = (acc0.z + acc1.z) * dinv;
  res.w = (acc0.w + acc1.w) * dinv;
  *reinterpret_cast<float4*>(&agg[(size_t)row * DDIM + lane * 4]) = res;
}

// out = agg @ W^T + x @ B^T, K=256 virtual (8 chunks of 32).
// agg aliases out: each block only ever reads the agg rows it later writes,
// and all its agg reads (chunks 0-3) complete before any thread epilogues.
__global__ __launch_bounds__(256) void gemm_k(const float* agg,
                                              const float* __restrict__ x,
                                              const float* __restrict__ W,
                                              const float* __restrict__ Bm,
                                              float* out) {
  __shared__ float sA[32][68];    // [k][row], float4-aligned stride
  __shared__ float sB[32][132];   // [k][col]
  int t = threadIdx.x;
  int tr = t >> 4;   // 0..15 -> 4 rows each
  int tc = t & 15;   // 0..15 -> cols tc*4..+3 and 64+tc*4..+3
  int row0 = blockIdx.x * 64;
  float acc[4][8];
#pragma unroll
  for (int i = 0; i < 4; ++i)
#pragma unroll
    for (int j = 0; j < 8; ++j) acc[i][j] = 0.0f;

  for (int ch = 0; ch < 8; ++ch) {
    const float* Ap = (ch < 4) ? agg : x;
    const float* Bp = (ch < 4) ? W : Bm;
    int kb = (ch & 3) * 32;
    __syncthreads();
#pragma unroll
    for (int u = 0; u < 2; ++u) {          // A tile: 64 rows x 32 k
      int f = t + u * 256;
      int rw = f >> 3, q = f & 7;
      float4 v = *reinterpret_cast<const float4*>(&Ap[(size_t)(row0 + rw) * DDIM + kb + q * 4]);
      sA[q * 4 + 0][rw] = v.x; sA[q * 4 + 1][rw] = v.y;
      sA[q * 4 + 2][rw] = v.z; sA[q * 4 + 3][rw] = v.w;
    }
#pragma unroll
    for (int u = 0; u < 4; ++u) {          // B tile: 128 cols x 32 k
      int f = t + u * 256;
      int cl = f >> 3, q = f & 7;
      float4 v = *reinterpret_cast<const float4*>(&Bp[(size_t)cl * DDIM + kb + q * 4]);
      sB[q * 4 + 0][cl] = v.x; sB[q * 4 + 1][cl] = v.y;
      sB[q * 4 + 2][cl] = v.z; sB[q * 4 + 3][cl] = v.w;
    }
    __syncthreads();
#pragma unroll 8
    for (int k = 0; k < 32; ++k) {
      float4 a  = *reinterpret_cast<const float4*>(&sA[k][tr * 4]);
      float4 b0 = *reinterpret_cast<const float4*>(&sB[k][tc * 4]);
      float4 b1 = *reinterpret_cast<const float4*>(&sB[k][64 + tc * 4]);
      const float av[4] = {a.x, a.y, a.z, a.w};
      const float bv[8] = {b0.x, b0.y, b0.z, b0.w, b1.x, b1.y, b1.z, b1.w};
#pragma unroll
      for (int i = 0; i < 4; ++i)
#pragma unroll
        for (int j = 0; j < 8; ++j) acc[i][j] += av[i] * bv[j];
    }
  }
#pragma unroll
  for (int i = 0; i < 4; ++i) {
    int row = row0 + tr * 4 + i;
    float4 o0 = {acc[i][0], acc[i][1], acc[i][2], acc[i][3]};
    float4 o1 = {acc[i][4], acc[i][5], acc[i][6], acc[i][7]};
    *reinterpret_cast<float4*>(&out[(size_t)row * DDIM + tc * 4]) = o0;
    *reinterpret_cast<float4*>(&out[(size_t)row * DDIM + 64 + tc * 4]) = o1;
  }
}

extern "C" void kernel_launch(void* const* d_in, const int* in_sizes, int n_in,
                              void* d_out, int out_size, void* d_ws, size_t ws_size,
                              hipStream_t stream) {
  const float* x = (const float*)d_in[0];
  const int* ei = (const int*)d_in[1];
  const float* W = (const float*)d_in[2];
  const float* Bm = (const float*)d_in[3];
  float* out = (float*)d_out;
  char* ws = (char*)d_ws;
  int* deg = (int*)(ws + OFF_DEG);
  int* rowptr = (int*)(ws + OFF_ROWPTR);
  int* flag = (int*)(ws + OFF_FLAG);
  int* cursor = (int*)(ws + OFF_CURSOR);
  int* col = (int*)(ws + OFF_COL);

  hipMemsetAsync(d_ws, 0, ZERO_BYTES, stream);
  detect_k<<<4, 256, 0, stream>>>(ei, flag);
  count_k<<<NEDGES / 256, 256, 0, stream>>>(ei, flag, deg);
  scan_k<<<1, 1024, 0, stream>>>(deg, rowptr);
  fill_k<<<NEDGES / 256, 256, 0, stream>>>(ei, flag, rowptr, cursor, col);
  gather_k<<<NNODES / RPB, 256, 0, stream>>>(rowptr, col, x, out);  // agg -> d_out
  gemm_k<<<NNODES / 64, 256, 0, stream>>>(out, x, W, Bm, out);
}

// Round 3
// 114.451 us; speedup vs baseline: 1.2477x; 1.0807x over previous
//
#include <hip/hip_runtime.h>

#define NNODES 16384
#define NEDGES 524288
#define DDIM   128

// workspace layout (bytes) — deg|cursor|flag contiguous so one zero kernel
// covers them with int4 stores. rowptr needs no zeroing (scan_k overwrites).
#define OFF_DEG     0u         // int[16384]
#define OFF_CURSOR  65536u     // int[16384]
#define OFF_FLAG    131072u    // int[4] (only [0] used)
#define OFF_ROWPTR  131136u    // int[16385]
#define OFF_COL     196736u    // int[524288]

// zero deg/cursor/flag: 131088 bytes = 8193 int4
__global__ __launch_bounds__(256) void zero_k(int4* __restrict__ ws) {
  int i = blockIdx.x * 256 + threadIdx.x;  // 0..8447 (33 blocks)
  if (i < 8193) ws[i] = int4{0, 0, 0, 0};
}

// Detect edge-index element width from data: if stored as int64, every odd
// int32 word is a high word == 0 (indices in [0,16384)). If int32, odd words
// are real indices, essentially never all zero over 1024 samples.
__global__ __launch_bounds__(256) void detect_k(const int* __restrict__ ei, int* __restrict__ flag) {
  int i = blockIdx.x * 256 + threadIdx.x;  // 0..1023
  if (ei[2 * i + 1] != 0) atomicOr(flag, 1);
}

__global__ __launch_bounds__(256) void count_k(const int* __restrict__ ei, const int* __restrict__ flag,
                                               int* __restrict__ deg) {
  int i = blockIdx.x * 256 + threadIdx.x;
  if (i < NEDGES) {
    int is32 = *flag;
    int d = is32 ? ei[NEDGES + i] : ei[2 * (NEDGES + i)];
    atomicAdd(&deg[d], 1);
  }
}

__global__ __launch_bounds__(1024) void scan_k(const int* __restrict__ deg, int* __restrict__ rowptr) {
  __shared__ int s[1024];
  int t = threadIdx.x;
  int base = t * 16;
  int v[16];
  int sum = 0;
#pragma unroll
  for (int j = 0; j < 16; ++j) { v[j] = deg[base + j]; sum += v[j]; }
  s[t] = sum;
  __syncthreads();
  for (int off = 1; off < 1024; off <<= 1) {
    int add = (t >= off) ? s[t - off] : 0;
    __syncthreads();
    s[t] += add;
    __syncthreads();
  }
  int run = (t == 0) ? 0 : s[t - 1];
#pragma unroll
  for (int j = 0; j < 16; ++j) { rowptr[base + j] = run; run += v[j]; }
  if (t == 1023) rowptr[NNODES] = run;
}

__global__ __launch_bounds__(256) void fill_k(const int* __restrict__ ei, const int* __restrict__ flag,
                                              const int* __restrict__ rowptr, int* __restrict__ cursor,
                                              int* __restrict__ col) {
  int i = blockIdx.x * 256 + threadIdx.x;
  if (i < NEDGES) {
    int is32 = *flag;
    int s = is32 ? ei[i] : ei[2 * i];
    int d = is32 ? ei[NEDGES + i] : ei[2 * (NEDGES + i)];
    int slot = rowptr[d] + atomicAdd(&cursor[d], 1);
    col[slot] = s;
  }
}

// mean in-degree 32 (Binomial(524288,1/16384)); max over 16384 rows ~60.
// CAP=128 is ~17 sigma beyond the mean: overflow prob ~1e-32.
#define CAP 128
#define RPB 8
// One row per 32-lane half-wave: all LDS traffic is intra-wave -> no barriers.
__global__ __launch_bounds__(256) void gather_k(const int* __restrict__ rowptr, const int* __restrict__ col,
                                                const float* __restrict__ x, float* __restrict__ agg) {
  __shared__ int   s_col[RPB][CAP];
  __shared__ float s_kf[RPB][CAP];
  int t = threadIdx.x;
  int lane = t & 31;   // float4 feature chunk
  int r = t >> 5;      // local row
  int row = blockIdx.x * RPB + r;
  int beg = rowptr[row];
  int k = rowptr[row + 1] - beg;
  if (k > CAP) k = CAP;

  for (int j = lane; j < k; j += 32) s_col[r][j] = col[beg + j];

  int lu = 0;
  for (int j = lane; j < k; j += 32) {
    int c = s_col[r][j];
    bool kp = true;
    for (int j2 = 0; j2 < j; ++j2)
      if (s_col[r][j2] == c) { kp = false; break; }
    s_kf[r][j] = kp ? 1.0f : 0.0f;
    lu += kp ? 1 : 0;
  }
#pragma unroll
  for (int off = 16; off; off >>= 1) lu += __shfl_xor(lu, off);
  float dinv = 1.0f / (float)(lu > 0 ? lu : 1);

  float4 acc0 = {0.f, 0.f, 0.f, 0.f}, acc1 = {0.f, 0.f, 0.f, 0.f};
  const float* xb = x + (size_t)lane * 4;
  int j = 0;
#pragma unroll 2
  for (; j + 2 <= k; j += 2) {
    int c0 = s_col[r][j], c1 = s_col[r][j + 1];
    float f0 = s_kf[r][j], f1 = s_kf[r][j + 1];
    float4 v0 = *reinterpret_cast<const float4*>(xb + (size_t)c0 * DDIM);
    float4 v1 = *reinterpret_cast<const float4*>(xb + (size_t)c1 * DDIM);
    acc0.x += f0 * v0.x; acc0.y += f0 * v0.y; acc0.z += f0 * v0.z; acc0.w += f0 * v0.w;
    acc1.x += f1 * v1.x; acc1.y += f1 * v1.y; acc1.z += f1 * v1.z; acc1.w += f1 * v1.w;
  }
  if (j < k) {
    int c0 = s_col[r][j];
    float f0 = s_kf[r][j];
    float4 v0 = *reinterpret_cast<const float4*>(xb + (size_t)c0 * DDIM);
    acc0.x += f0 * v0.x; acc0.y += f0 * v0.y; acc0.z += f0 * v0.z; acc0.w += f0 * v0.w;
  }
  float4 res;
  res.x = (acc0.x + acc1.x) * dinv;
  res.y = (acc0.y + acc1.y) * dinv;
  res.z = (acc0.z + acc1.z) * dinv;
  res.w = (acc0.w + acc1.w) * dinv;
  *reinterpret_cast<float4*>(&agg[(size_t)row * DDIM + lane * 4]) = res;
}

// out = agg @ W^T + x @ B^T, K=256 virtual (8 chunks of 32).
// agg aliases out: each block only ever reads the agg rows it later writes,
// and all its agg reads (chunks 0-3) complete before any epilogue store.
__global__ __launch_bounds__(256) void gemm_k(const float* agg,
                                              const float* __restrict__ x,
                                              const float* __restrict__ W,
                                              const float* __restrict__ Bm,
                                              float* out) {
  __shared__ float sA[32][68];    // [k][row], float4-aligned stride
  __shared__ float sB[32][132];   // [k][col]
  int t = threadIdx.x;
  int tr = t >> 4;   // 0..15 -> 4 rows each
  int tc = t & 15;   // 0..15 -> cols tc*4..+3 and 64+tc*4..+3
  int row0 = blockIdx.x * 64;
  float acc[4][8];
#pragma unroll
  for (int i = 0; i < 4; ++i)
#pragma unroll
    for (int j = 0; j < 8; ++j) acc[i][j] = 0.0f;

  for (int ch = 0; ch < 8; ++ch) {
    const float* Ap = (ch < 4) ? agg : x;
    const float* Bp = (ch < 4) ? W : Bm;
    int kb = (ch & 3) * 32;
    __syncthreads();
#pragma unroll
    for (int u = 0; u < 2; ++u) {          // A tile: 64 rows x 32 k
      int f = t + u * 256;
      int rw = f >> 3, q = f & 7;
      float4 v = *reinterpret_cast<const float4*>(&Ap[(size_t)(row0 + rw) * DDIM + kb + q * 4]);
      sA[q * 4 + 0][rw] = v.x; sA[q * 4 + 1][rw] = v.y;
      sA[q * 4 + 2][rw] = v.z; sA[q * 4 + 3][rw] = v.w;
    }
#pragma unroll
    for (int u = 0; u < 4; ++u) {          // B tile: 128 cols x 32 k
      int f = t + u * 256;
      int cl = f >> 3, q = f & 7;
      float4 v = *reinterpret_cast<const float4*>(&Bp[(size_t)cl * DDIM + kb + q * 4]);
      sB[q * 4 + 0][cl] = v.x; sB[q * 4 + 1][cl] = v.y;
      sB[q * 4 + 2][cl] = v.z; sB[q * 4 + 3][cl] = v.w;
    }
    __syncthreads();
#pragma unroll 8
    for (int k = 0; k < 32; ++k) {
      float4 a  = *reinterpret_cast<const float4*>(&sA[k][tr * 4]);
      float4 b0 = *reinterpret_cast<const float4*>(&sB[k][tc * 4]);
      float4 b1 = *reinterpret_cast<const float4*>(&sB[k][64 + tc * 4]);
      const float av[4] = {a.x, a.y, a.z, a.w};
      const float bv[8] = {b0.x, b0.y, b0.z, b0.w, b1.x, b1.y, b1.z, b1.w};
#pragma unroll
      for (int i = 0; i < 4; ++i)
#pragma unroll
        for (int j = 0; j < 8; ++j) acc[i][j] += av[i] * bv[j];
    }
  }
#pragma unroll
  for (int i = 0; i < 4; ++i) {
    int row = row0 + tr * 4 + i;
    float4 o0 = {acc[i][0], acc[i][1], acc[i][2], acc[i][3]};
    float4 o1 = {acc[i][4], acc[i][5], acc[i][6], acc[i][7]};
    *reinterpret_cast<float4*>(&out[(size_t)row * DDIM + tc * 4]) = o0;
    *reinterpret_cast<float4*>(&out[(size_t)row * DDIM + 64 + tc * 4]) = o1;
  }
}

extern "C" void kernel_launch(void* const* d_in, const int* in_sizes, int n_in,
                              void* d_out, int out_size, void* d_ws, size_t ws_size,
                              hipStream_t stream) {
  const float* x = (const float*)d_in[0];
  const int* ei = (const int*)d_in[1];
  const float* W = (const float*)d_in[2];
  const float* Bm = (const float*)d_in[3];
  float* out = (float*)d_out;
  char* ws = (char*)d_ws;
  int* deg = (int*)(ws + OFF_DEG);
  int* cursor = (int*)(ws + OFF_CURSOR);
  int* flag = (int*)(ws + OFF_FLAG);
  int* rowptr = (int*)(ws + OFF_ROWPTR);
  int* col = (int*)(ws + OFF_COL);

  zero_k<<<33, 256, 0, stream>>>((int4*)ws);
  detect_k<<<4, 256, 0, stream>>>(ei, flag);
  count_k<<<NEDGES / 256, 256, 0, stream>>>(ei, flag, deg);
  scan_k<<<1, 1024, 0, stream>>>(deg, rowptr);
  fill_k<<<NEDGES / 256, 256, 0, stream>>>(ei, flag, rowptr, cursor, col);
  gather_k<<<NNODES / RPB, 256, 0, stream>>>(rowptr, col, x, out);  // agg -> d_out
  gemm_k<<<NNODES / 64, 256, 0, stream>>>(out, x, W, Bm, out);
}

// Round 4
// 72.948 us; speedup vs baseline: 1.9576x; 1.5689x over previous
//
#include <hip/hip_runtime.h>

#define NNODES 16384
#define NEDGES 524288
#define DDIM   128
#define CAP    128   // max in-degree slab slots; Binomial(524288,1/16384), P(>128)~1e-32

// workspace layout (bytes)
#define OFF_CNT   0u          // int[16384]
#define OFF_FLAG  65536u      // int[16] (only [0] used; 1 => edges are int32)
#define OFF_SLAB  69632u      // int[16384*128] = 8 MB

typedef __bf16 bf16x8 __attribute__((ext_vector_type(8)));
typedef __bf16 bf16x4 __attribute__((ext_vector_type(4)));
typedef float  f32x4  __attribute__((ext_vector_type(4)));

// blocks 0..15: zero cnt (4096 int4). block 16: detect edge width -> flag.
// int64 edges => every odd int32 word is a zero high-word; int32 => ~never.
__global__ __launch_bounds__(256) void prep_k(int4* __restrict__ cnt4,
                                              const int* __restrict__ ei,
                                              int* __restrict__ flag) {
  int b = blockIdx.x, t = threadIdx.x;
  if (b < 16) {
    cnt4[b * 256 + t] = int4{0, 0, 0, 0};
  } else {
    __shared__ int s_any;
    if (t == 0) s_any = 0;
    __syncthreads();
    if (ei[2 * t + 1] != 0) atomicOr(&s_any, 1);
    __syncthreads();
    if (t == 0) flag[0] = s_any ? 1 : 0;
  }
}

__global__ __launch_bounds__(256) void fill_k(const int* __restrict__ ei, const int* __restrict__ flag,
                                              int* __restrict__ cnt, int* __restrict__ slab) {
  int i = blockIdx.x * 256 + threadIdx.x;
  if (i < NEDGES) {
    int is32 = *flag;
    int s = is32 ? ei[i] : ei[2 * i];
    int d = is32 ? ei[NEDGES + i] : ei[2 * (NEDGES + i)];
    int slot = atomicAdd(&cnt[d], 1);
    if (slot < CAP) slab[(size_t)d * CAP + slot] = s;
  }
}

#define RPB 8
// One row per 32-lane half-wave; all LDS traffic intra-wave -> no barriers.
__global__ __launch_bounds__(256) void gather_k(const int* __restrict__ cnt, const int* __restrict__ slab,
                                                const float* __restrict__ x, float* __restrict__ agg) {
  __shared__ int   s_col[RPB][CAP];
  __shared__ float s_kf[RPB][CAP];
  int t = threadIdx.x;
  int lane = t & 31;   // float4 feature chunk
  int r = t >> 5;      // local row
  int row = blockIdx.x * RPB + r;
  int k = cnt[row];
  if (k > CAP) k = CAP;
  const int* srow = slab + (size_t)row * CAP;

  for (int j = lane; j < k; j += 32) s_col[r][j] = srow[j];

  int lu = 0;
  for (int j = lane; j < k; j += 32) {
    int c = s_col[r][j];
    bool kp = true;
    for (int j2 = 0; j2 < j; ++j2)
      if (s_col[r][j2] == c) { kp = false; break; }
    s_kf[r][j] = kp ? 1.0f : 0.0f;
    lu += kp ? 1 : 0;
  }
#pragma unroll
  for (int off = 16; off; off >>= 1) lu += __shfl_xor(lu, off);
  float dinv = 1.0f / (float)(lu > 0 ? lu : 1);

  float4 a0 = {0,0,0,0}, a1 = {0,0,0,0}, a2 = {0,0,0,0}, a3 = {0,0,0,0};
  const float* xb = x + (size_t)lane * 4;
  int j = 0;
  for (; j + 4 <= k; j += 4) {
    int c0 = s_col[r][j], c1 = s_col[r][j+1], c2 = s_col[r][j+2], c3 = s_col[r][j+3];
    float f0 = s_kf[r][j], f1 = s_kf[r][j+1], f2 = s_kf[r][j+2], f3 = s_kf[r][j+3];
    float4 v0 = *reinterpret_cast<const float4*>(xb + (size_t)c0 * DDIM);
    float4 v1 = *reinterpret_cast<const float4*>(xb + (size_t)c1 * DDIM);
    float4 v2 = *reinterpret_cast<const float4*>(xb + (size_t)c2 * DDIM);
    float4 v3 = *reinterpret_cast<const float4*>(xb + (size_t)c3 * DDIM);
    a0.x += f0*v0.x; a0.y += f0*v0.y; a0.z += f0*v0.z; a0.w += f0*v0.w;
    a1.x += f1*v1.x; a1.y += f1*v1.y; a1.z += f1*v1.z; a1.w += f1*v1.w;
    a2.x += f2*v2.x; a2.y += f2*v2.y; a2.z += f2*v2.z; a2.w += f2*v2.w;
    a3.x += f3*v3.x; a3.y += f3*v3.y; a3.z += f3*v3.z; a3.w += f3*v3.w;
  }
  for (; j < k; ++j) {
    int c0 = s_col[r][j];
    float f0 = s_kf[r][j];
    float4 v0 = *reinterpret_cast<const float4*>(xb + (size_t)c0 * DDIM);
    a0.x += f0*v0.x; a0.y += f0*v0.y; a0.z += f0*v0.z; a0.w += f0*v0.w;
  }
  float4 res;
  res.x = (a0.x + a1.x + a2.x + a3.x) * dinv;
  res.y = (a0.y + a1.y + a2.y + a3.y) * dinv;
  res.z = (a0.z + a1.z + a2.z + a3.z) * dinv;
  res.w = (a0.w + a1.w + a2.w + a3.w) * dinv;
  *reinterpret_cast<float4*>(&agg[(size_t)row * DDIM + lane * 4]) = res;
}

// out = agg @ W^T + x @ B^T via bf16 MFMA, K=256 virtual (8 chunks of 32).
// Block tile 128 rows x 128 cols; 4 waves, each 32 rows x 128 cols.
// agg aliases out: all agg reads (kc 0..3 staging) complete before epilogue.
__global__ __launch_bounds__(256) void gemm_k(const float* agg,
                                              const float* __restrict__ x,
                                              const float* __restrict__ W,
                                              const float* __restrict__ Bm,
                                              float* out) {
  __shared__ __bf16 sA[128][40];   // [row][k], stride 40 bf16 = 80 B (16B-aligned)
  __shared__ __bf16 sB[128][40];   // [n][k]
  int t = threadIdx.x;
  int l = t & 63, wid = t >> 6;
  int g = l >> 4, ln = l & 15;     // k-group (0..3), m/n-lane (0..15)
  int row0 = blockIdx.x * 128;
  int wr0 = wid * 32;

  f32x4 acc[2][8];
#pragma unroll
  for (int mb = 0; mb < 2; ++mb)
#pragma unroll
    for (int nb = 0; nb < 8; ++nb) acc[mb][nb] = f32x4{0.f, 0.f, 0.f, 0.f};

  for (int kc = 0; kc < 8; ++kc) {
    const float* Ap = (kc < 4) ? agg : x;
    const float* Bp = (kc < 4) ? W : Bm;
    int kb = (kc & 3) * 32;
    __syncthreads();
#pragma unroll
    for (int u = 0; u < 4; ++u) {       // A: 128 rows x 32 k
      int f = u * 256 + t;
      int rr = f >> 3, q = f & 7;
      float4 v = *reinterpret_cast<const float4*>(&Ap[(size_t)(row0 + rr) * DDIM + kb + q * 4]);
      bf16x4 w = {(__bf16)v.x, (__bf16)v.y, (__bf16)v.z, (__bf16)v.w};
      *reinterpret_cast<bf16x4*>(&sA[rr][q * 4]) = w;
    }
#pragma unroll
    for (int u = 0; u < 4; ++u) {       // B: 128 n x 32 k
      int f = u * 256 + t;
      int rr = f >> 3, q = f & 7;
      float4 v = *reinterpret_cast<const float4*>(&Bp[(size_t)rr * DDIM + kb + q * 4]);
      bf16x4 w = {(__bf16)v.x, (__bf16)v.y, (__bf16)v.z, (__bf16)v.w};
      *reinterpret_cast<bf16x4*>(&sB[rr][q * 4]) = w;
    }
    __syncthreads();

    bf16x8 afr[2], bfr[8];
#pragma unroll
    for (int mb = 0; mb < 2; ++mb)
      afr[mb] = *reinterpret_cast<const bf16x8*>(&sA[wr0 + mb * 16 + ln][g * 8]);
#pragma unroll
    for (int nb = 0; nb < 8; ++nb)
      bfr[nb] = *reinterpret_cast<const bf16x8*>(&sB[nb * 16 + ln][g * 8]);
#pragma unroll
    for (int mb = 0; mb < 2; ++mb)
#pragma unroll
      for (int nb = 0; nb < 8; ++nb)
        acc[mb][nb] = __builtin_amdgcn_mfma_f32_16x16x32_bf16(afr[mb], bfr[nb], acc[mb][nb], 0, 0, 0);
  }

  // C/D layout: col = lane&15, row = (lane>>4)*4 + i   [verified m89/m91]
#pragma unroll
  for (int mb = 0; mb < 2; ++mb)
#pragma unroll
    for (int nb = 0; nb < 8; ++nb)
#pragma unroll
      for (int i = 0; i < 4; ++i)
        out[(size_t)(row0 + wr0 + mb * 16 + g * 4 + i) * DDIM + nb * 16 + ln] = acc[mb][nb][i];
}

extern "C" void kernel_launch(void* const* d_in, const int* in_sizes, int n_in,
                              void* d_out, int out_size, void* d_ws, size_t ws_size,
                              hipStream_t stream) {
  const float* x = (const float*)d_in[0];
  const int* ei = (const int*)d_in[1];
  const float* W = (const float*)d_in[2];
  const float* Bm = (const float*)d_in[3];
  float* out = (float*)d_out;
  char* ws = (char*)d_ws;
  int* cnt = (int*)(ws + OFF_CNT);
  int* flag = (int*)(ws + OFF_FLAG);
  int* slab = (int*)(ws + OFF_SLAB);

  prep_k<<<17, 256, 0, stream>>>((int4*)cnt, ei, flag);
  fill_k<<<NEDGES / 256, 256, 0, stream>>>(ei, flag, cnt, slab);
  gather_k<<<NNODES / RPB, 256, 0, stream>>>(cnt, slab, x, out);   // agg -> d_out
  gemm_k<<<NNODES / 128, 256, 0, stream>>>(out, x, W, Bm, out);
}

// Round 5
// 71.946 us; speedup vs baseline: 1.9849x; 1.0139x over previous
//
#include <hip/hip_runtime.h>

#define NNODES 16384
#define NEDGES 524288
#define DDIM   128
#define CAP    128   // max in-degree slots; Poisson(32) tail P(>128) ~ 1e-43

// workspace layout (bytes)
#define OFF_CNT   0u          // int[16384]
#define OFF_FLAG  65536u      // int[16] (only [0]; 1 => edges are int32)
#define OFF_SLAB  69632u      // int[16384*128] = 8 MB
#define OFF_XB    8458240u    // bf16[16384*128] = 4 MB
#define WS_NEED   12652544u

typedef __bf16 bf16x8 __attribute__((ext_vector_type(8)));
typedef __bf16 bf16x4 __attribute__((ext_vector_type(4)));
typedef float  f32x4  __attribute__((ext_vector_type(4)));
typedef unsigned short u16;

// blocks [0,nconv): x -> bf16 copy. next 16: zero cnt. last: detect edge width.
__global__ __launch_bounds__(256) void prep_k(int nconv,
                                              const float* __restrict__ x,
                                              __bf16* __restrict__ xb,
                                              int4* __restrict__ cnt4,
                                              const int* __restrict__ ei,
                                              int* __restrict__ flag) {
  int b = blockIdx.x, t = threadIdx.x;
  if (b < nconv) {
    int i = b * 256 + t;                     // 4 floats each
    float4 v = reinterpret_cast<const float4*>(x)[i];
    bf16x4 w = {(__bf16)v.x, (__bf16)v.y, (__bf16)v.z, (__bf16)v.w};
    reinterpret_cast<bf16x4*>(xb)[i] = w;
  } else if (b < nconv + 16) {
    cnt4[(b - nconv) * 256 + t] = int4{0, 0, 0, 0};
  } else {
    __shared__ int s_any;
    if (t == 0) s_any = 0;
    __syncthreads();
    if (ei[2 * t + 1] != 0) atomicOr(&s_any, 1);
    __syncthreads();
    if (t == 0) flag[0] = s_any ? 1 : 0;
  }
}

__global__ __launch_bounds__(256) void fill_k(const int* __restrict__ ei, const int* __restrict__ flag,
                                              int* __restrict__ cnt, int* __restrict__ slab) {
  int i = blockIdx.x * 256 + threadIdx.x;
  if (i < NEDGES) {
    int is32 = *flag;
    int s = is32 ? ei[i] : ei[2 * i];
    int d = is32 ? ei[NEDGES + i] : ei[2 * (NEDGES + i)];
    int slot = atomicAdd(&cnt[d], 1);
    if (slot < CAP) slab[(size_t)d * CAP + slot] = s;
  }
}

// ---- bf16 gather: one row per 16-lane group (bf16x8 = 16B per lane) ----
#define RPB 16
__global__ __launch_bounds__(256) void gather_bf_k(const int* __restrict__ cnt,
                                                   const int* __restrict__ slab,
                                                   const u16* __restrict__ xb,
                                                   float* __restrict__ agg) {
  __shared__ int   s_col[RPB][CAP];
  __shared__ float s_kf[RPB][CAP];
  int t = threadIdx.x;
  int lane = t & 15, r = t >> 4;
  int row = blockIdx.x * RPB + r;
  int k = cnt[row];
  if (k > CAP) k = CAP;
  const int* srow = slab + (size_t)row * CAP;

  for (int j = lane; j < k; j += 16) s_col[r][j] = srow[j];

  int lu = 0;
  for (int j = lane; j < k; j += 16) {
    int c = s_col[r][j];
    bool kp = true;
    for (int j2 = 0; j2 < j; ++j2)
      if (s_col[r][j2] == c) { kp = false; break; }
    s_kf[r][j] = kp ? 1.0f : 0.0f;
    lu += kp ? 1 : 0;
  }
#pragma unroll
  for (int off = 8; off; off >>= 1) lu += __shfl_xor(lu, off);
  float dinv = 1.0f / (float)(lu > 0 ? lu : 1);

  float acc[8] = {0, 0, 0, 0, 0, 0, 0, 0};
  const u16* xbl = xb + (size_t)lane * 8;
  int j = 0;
  for (; j + 2 <= k; j += 2) {
    int c0 = s_col[r][j], c1 = s_col[r][j + 1];
    float f0 = s_kf[r][j], f1 = s_kf[r][j + 1];
    uint4 v0 = *reinterpret_cast<const uint4*>(xbl + (size_t)c0 * DDIM);
    uint4 v1 = *reinterpret_cast<const uint4*>(xbl + (size_t)c1 * DDIM);
    const unsigned* w0 = reinterpret_cast<const unsigned*>(&v0);
    const unsigned* w1 = reinterpret_cast<const unsigned*>(&v1);
#pragma unroll
    for (int q = 0; q < 4; ++q) {
      acc[2*q]   += f0 * __uint_as_float(w0[q] << 16);
      acc[2*q+1] += f0 * __uint_as_float(w0[q] & 0xffff0000u);
      acc[2*q]   += f1 * __uint_as_float(w1[q] << 16);
      acc[2*q+1] += f1 * __uint_as_float(w1[q] & 0xffff0000u);
    }
  }
  if (j < k) {
    float f0 = s_kf[r][j];
    uint4 v0 = *reinterpret_cast<const uint4*>(xbl + (size_t)s_col[r][j] * DDIM);
    const unsigned* w0 = reinterpret_cast<const unsigned*>(&v0);
#pragma unroll
    for (int q = 0; q < 4; ++q) {
      acc[2*q]   += f0 * __uint_as_float(w0[q] << 16);
      acc[2*q+1] += f0 * __uint_as_float(w0[q] & 0xffff0000u);
    }
  }
  float4 o0 = {acc[0]*dinv, acc[1]*dinv, acc[2]*dinv, acc[3]*dinv};
  float4 o1 = {acc[4]*dinv, acc[5]*dinv, acc[6]*dinv, acc[7]*dinv};
  float* dst = &agg[(size_t)row * DDIM + lane * 8];
  *reinterpret_cast<float4*>(dst) = o0;
  *reinterpret_cast<float4*>(dst + 4) = o1;
}

// ---- fallback fp32 gather (round-4 version, used if ws too small) ----
#define RPB32 8
__global__ __launch_bounds__(256) void gather_k(const int* __restrict__ cnt, const int* __restrict__ slab,
                                                const float* __restrict__ x, float* __restrict__ agg) {
  __shared__ int   s_col[RPB32][CAP];
  __shared__ float s_kf[RPB32][CAP];
  int t = threadIdx.x;
  int lane = t & 31, r = t >> 5;
  int row = blockIdx.x * RPB32 + r;
  int k = cnt[row];
  if (k > CAP) k = CAP;
  const int* srow = slab + (size_t)row * CAP;
  for (int j = lane; j < k; j += 32) s_col[r][j] = srow[j];
  int lu = 0;
  for (int j = lane; j < k; j += 32) {
    int c = s_col[r][j];
    bool kp = true;
    for (int j2 = 0; j2 < j; ++j2)
      if (s_col[r][j2] == c) { kp = false; break; }
    s_kf[r][j] = kp ? 1.0f : 0.0f;
    lu += kp ? 1 : 0;
  }
#pragma unroll
  for (int off = 16; off; off >>= 1) lu += __shfl_xor(lu, off);
  float dinv = 1.0f / (float)(lu > 0 ? lu : 1);
  float4 a0 = {0,0,0,0}, a1 = {0,0,0,0};
  const float* xb = x + (size_t)lane * 4;
  int j = 0;
  for (; j + 2 <= k; j += 2) {
    int c0 = s_col[r][j], c1 = s_col[r][j+1];
    float f0 = s_kf[r][j], f1 = s_kf[r][j+1];
    float4 v0 = *reinterpret_cast<const float4*>(xb + (size_t)c0 * DDIM);
    float4 v1 = *reinterpret_cast<const float4*>(xb + (size_t)c1 * DDIM);
    a0.x += f0*v0.x; a0.y += f0*v0.y; a0.z += f0*v0.z; a0.w += f0*v0.w;
    a1.x += f1*v1.x; a1.y += f1*v1.y; a1.z += f1*v1.z; a1.w += f1*v1.w;
  }
  if (j < k) {
    float f0 = s_kf[r][j];
    float4 v0 = *reinterpret_cast<const float4*>(xb + (size_t)s_col[r][j] * DDIM);
    a0.x += f0*v0.x; a0.y += f0*v0.y; a0.z += f0*v0.z; a0.w += f0*v0.w;
  }
  float4 res = {(a0.x+a1.x)*dinv, (a0.y+a1.y)*dinv, (a0.z+a1.z)*dinv, (a0.w+a1.w)*dinv};
  *reinterpret_cast<float4*>(&agg[(size_t)row * DDIM + lane * 4]) = res;
}

// out = agg @ W^T + x @ B^T via bf16 MFMA, K=256 virtual (8 chunks of 32).
// BM=64 (256 blocks), 4 waves x 16 rows x 128 cols.
// agg aliases out: all agg reads (kc<4 staging) precede the epilogue.
template<int USE_XB>
__global__ __launch_bounds__(256) void gemm_k(const float* agg,
                                              const float* __restrict__ x,
                                              const u16* __restrict__ xb,
                                              const float* __restrict__ W,
                                              const float* __restrict__ Bm,
                                              float* out) {
  __shared__ __bf16 sA[64][40];    // [row][k], stride 80B
  __shared__ __bf16 sB[128][40];   // [n][k]
  int t = threadIdx.x;
  int l = t & 63, wid = t >> 6;
  int g = l >> 4, ln = l & 15;
  int row0 = blockIdx.x * 64;
  int wr0 = wid * 16;

  f32x4 acc[8];
#pragma unroll
  for (int nb = 0; nb < 8; ++nb) acc[nb] = f32x4{0.f, 0.f, 0.f, 0.f};

  for (int kc = 0; kc < 8; ++kc) {
    int kb = (kc & 3) * 32;
    __syncthreads();
    if (kc < 4) {
#pragma unroll
      for (int u = 0; u < 2; ++u) {       // A: 64 rows x 32 k from agg (fp32)
        int f = u * 256 + t;
        int rr = f >> 3, q = f & 7;
        float4 v = *reinterpret_cast<const float4*>(&agg[(size_t)(row0 + rr) * DDIM + kb + q * 4]);
        bf16x4 w = {(__bf16)v.x, (__bf16)v.y, (__bf16)v.z, (__bf16)v.w};
        *reinterpret_cast<bf16x4*>(&sA[rr][q * 4]) = w;
      }
    } else if (USE_XB) {
      int rr = t >> 2, q = t & 3;         // A: 64 rows x 32 k from xb (bf16 copy)
      uint4 v = *reinterpret_cast<const uint4*>(&xb[(size_t)(row0 + rr) * DDIM + kb + q * 8]);
      *reinterpret_cast<uint4*>(&sA[rr][q * 8]) = v;
    } else {
#pragma unroll
      for (int u = 0; u < 2; ++u) {       // A from x (fp32)
        int f = u * 256 + t;
        int rr = f >> 3, q = f & 7;
        float4 v = *reinterpret_cast<const float4*>(&x[(size_t)(row0 + rr) * DDIM + kb + q * 4]);
        bf16x4 w = {(__bf16)v.x, (__bf16)v.y, (__bf16)v.z, (__bf16)v.w};
        *reinterpret_cast<bf16x4*>(&sA[rr][q * 4]) = w;
      }
    }
    {
      const float* Bp = (kc < 4) ? W : Bm;
#pragma unroll
      for (int u = 0; u < 4; ++u) {       // B: 128 n x 32 k
        int f = u * 256 + t;
        int rr = f >> 3, q = f & 7;
        float4 v = *reinterpret_cast<const float4*>(&Bp[(size_t)rr * DDIM + kb + q * 4]);
        bf16x4 w = {(__bf16)v.x, (__bf16)v.y, (__bf16)v.z, (__bf16)v.w};
        *reinterpret_cast<bf16x4*>(&sB[rr][q * 4]) = w;
      }
    }
    __syncthreads();

    bf16x8 afr = *reinterpret_cast<const bf16x8*>(&sA[wr0 + ln][g * 8]);
    bf16x8 bfr[8];
#pragma unroll
    for (int nb = 0; nb < 8; ++nb)
      bfr[nb] = *reinterpret_cast<const bf16x8*>(&sB[nb * 16 + ln][g * 8]);
#pragma unroll
    for (int nb = 0; nb < 8; ++nb)
      acc[nb] = __builtin_amdgcn_mfma_f32_16x16x32_bf16(afr, bfr[nb], acc[nb], 0, 0, 0);
  }

  // C/D layout: col = lane&15, row = (lane>>4)*4 + i  [verified m89/m91]
#pragma unroll
  for (int nb = 0; nb < 8; ++nb)
#pragma unroll
    for (int i = 0; i < 4; ++i)
      out[(size_t)(row0 + wr0 + g * 4 + i) * DDIM + nb * 16 + ln] = acc[nb][i];
}

extern "C" void kernel_launch(void* const* d_in, const int* in_sizes, int n_in,
                              void* d_out, int out_size, void* d_ws, size_t ws_size,
                              hipStream_t stream) {
  const float* x = (const float*)d_in[0];
  const int* ei = (const int*)d_in[1];
  const float* W = (const float*)d_in[2];
  const float* Bm = (const float*)d_in[3];
  float* out = (float*)d_out;
  char* ws = (char*)d_ws;
  int* cnt = (int*)(ws + OFF_CNT);
  int* flag = (int*)(ws + OFF_FLAG);
  int* slab = (int*)(ws + OFF_SLAB);
  __bf16* xb = (__bf16*)(ws + OFF_XB);

  const bool use_xb = (ws_size >= WS_NEED);
  const int nconv = use_xb ? 2048 : 0;

  prep_k<<<nconv + 17, 256, 0, stream>>>(nconv, x, xb, (int4*)cnt, ei, flag);
  fill_k<<<NEDGES / 256, 256, 0, stream>>>(ei, flag, cnt, slab);
  if (use_xb) {
    gather_bf_k<<<NNODES / RPB, 256, 0, stream>>>(cnt, slab, (const u16*)xb, out);
    gemm_k<1><<<NNODES / 64, 256, 0, stream>>>(out, x, (const u16*)xb, W, Bm, out);
  } else {
    gather_k<<<NNODES / RPB32, 256, 0, stream>>>(cnt, slab, x, out);
    gemm_k<0><<<NNODES / 64, 256, 0, stream>>>(out, x, (const u16*)xb, W, Bm, out);
  }
}